// Round 9
// baseline (38.442 us; speedup 1.0000x reference)
//
#include <hip/hip_runtime.h>

#define SMOOTHF 0.001f
#define DICE_WF 0.8f

constexpr int N_B = 16, N_C = 3, N_H = 512, N_W = 512;
constexpr int SLICES    = N_B * N_C;          // 48
constexpr int ELEMS     = N_H * N_W;          // 262144 elements per (b,c) slice
constexpr int TPB       = 256;
constexpr int BPS       = 32;                 // blocks per slice (R2 config)
constexpr int NBLK      = SLICES * BPS;       // 1536 stage1 blocks
constexpr int V4_SLICE  = ELEMS / 4;          // 65536 float4 per slice
constexpr int V4_BLOCK  = V4_SLICE / BPS;     // 2048 float4 per block
constexpr int V4_THREAD = V4_BLOCK / TPB;     // 8 float4 per thread
constexpr int WS_FLOATS = 5 * NBLK;           // SoA partials: ws[comp][NBLK]

// MEASUREMENT ROUND: stage1 is launched TWICE (idempotent — pure function of
// inputs, rewrites identical values). dur_us - 23.13 isolates warm stage1.

// Five linear accumulators (targets are exactly {0,1}):
//   sp = Σ sigmoid(x)   pt = Σ sigmoid(x)·t   st = Σ t
//   sd = Σ (x−t)²       sdt = Σ (x−t)²·t
struct Acc { float sp, pt, st, sd, sdt; };

__device__ __forceinline__ void acc1(float x, float t, Acc& a) {
    float e  = __expf(-x);
    float p  = __builtin_amdgcn_rcpf(1.0f + e);  // sigmoid via v_rcp
    float d  = x - t;
    float d2 = d * d;
    a.sp += p;
    a.pt  = fmaf(p, t, a.pt);
    a.st += t;
    a.sd += d2;
    a.sdt = fmaf(d2, t, a.sdt);
}

__device__ __forceinline__ void waveReduce5(Acc& a) {
    #pragma unroll
    for (int off = 32; off > 0; off >>= 1) {
        a.sp  += __shfl_down(a.sp,  off, 64);
        a.pt  += __shfl_down(a.pt,  off, 64);
        a.st  += __shfl_down(a.st,  off, 64);
        a.sd  += __shfl_down(a.sd,  off, 64);
        a.sdt += __shfl_down(a.sdt, off, 64);
    }
}

// Stage 1: exactly R2's kernel (23.13 µs total structure).
__global__ __launch_bounds__(TPB) void stage1(const float4* __restrict__ lg,
                                              const float4* __restrict__ tg,
                                              float* __restrict__ ws) {
    const int blk  = blockIdx.x;
    const int tid  = (int)threadIdx.x;
    const int base = blk * V4_BLOCK + tid;
    Acc a{0.f, 0.f, 0.f, 0.f, 0.f};
    #pragma unroll
    for (int k = 0; k < V4_THREAD; ++k) {
        float4 x4 = lg[base + k * TPB];
        float4 t4 = tg[base + k * TPB];
        acc1(x4.x, t4.x, a); acc1(x4.y, t4.y, a);
        acc1(x4.z, t4.z, a); acc1(x4.w, t4.w, a);
    }
    waveReduce5(a);
    __shared__ float red[TPB / 64][5];
    const int wave = tid >> 6;
    if ((tid & 63) == 0) {
        red[wave][0] = a.sp; red[wave][1] = a.pt; red[wave][2] = a.st;
        red[wave][3] = a.sd; red[wave][4] = a.sdt;
    }
    __syncthreads();
    if (tid < 5) {
        float v = 0.f;
        #pragma unroll
        for (int w = 0; w < TPB / 64; ++w) v += red[w][tid];
        ws[tid * NBLK + blk] = v;
    }
}

// Stage 2: exactly R2's kernel.
__global__ __launch_bounds__(64) void stage2(const float* __restrict__ ws,
                                             float* __restrict__ out) {
    const int t = threadIdx.x;
    float dice = 0.f, mse = 0.f;
    if (t < SLICES) {
        float c[5];
        #pragma unroll
        for (int comp = 0; comp < 5; ++comp) {
            const float4* p = (const float4*)(ws + comp * NBLK + t * BPS);
            float4 s = {0.f, 0.f, 0.f, 0.f};
            #pragma unroll
            for (int k = 0; k < BPS / 4; ++k) {
                float4 v = p[k];
                s.x += v.x; s.y += v.y; s.z += v.z; s.w += v.w;
            }
            c[comp] = (s.x + s.y) + (s.z + s.w);
        }
        float sp = c[0], pt = c[1], st = c[2], sd = c[3], sdt = c[4];
        dice = (2.0f * pt + SMOOTHF) / (sp + st + SMOOTHF);
        float cp = st;
        float cn = (float)ELEMS - cp;
        float s1 = sdt, s0 = sd - sdt;
        float mp = (cp > 0.f) ? s1 / fmaxf(cp, 1.f) : 0.f;
        float mn = (cn > 0.f) ? s0 / fmaxf(cn, 1.f) : 0.f;
        mse = mp + mn;
    }
    #pragma unroll
    for (int off = 32; off > 0; off >>= 1) {
        dice += __shfl_down(dice, off, 64);
        mse  += __shfl_down(mse,  off, 64);
    }
    if (t == 0) {
        float dice_loss = 1.0f - dice / (float)SLICES;
        float mse_loss  = mse / (float)SLICES;
        out[0] = DICE_WF * dice_loss + (1.0f - DICE_WF) * mse_loss;
    }
}

extern "C" void kernel_launch(void* const* d_in, const int* in_sizes, int n_in,
                              void* d_out, int out_size, void* d_ws, size_t ws_size,
                              hipStream_t stream) {
    const float4* lg = (const float4*)d_in[0];
    const float4* tg = (const float4*)d_in[1];
    float* out = (float*)d_out;
    float* ws  = (float*)d_ws;
    stage1<<<NBLK, TPB, 0, stream>>>(lg, tg, ws);   // measurement copy
    stage1<<<NBLK, TPB, 0, stream>>>(lg, tg, ws);   // idempotent rewrite
    stage2<<<1, 64, 0, stream>>>(ws, out);
}

// Round 10
// 25.559 us; speedup vs baseline: 1.5040x; 1.5040x over previous
//
#include <hip/hip_runtime.h>

#define SMOOTHF 0.001f
#define DICE_WF 0.8f

constexpr int N_B = 16, N_C = 3, N_H = 512, N_W = 512;
constexpr int SLICES    = N_B * N_C;          // 48
constexpr int ELEMS     = N_H * N_W;          // 262144 elements per (b,c) slice
constexpr int TPB       = 256;
constexpr int BPS       = 32;                 // blocks per slice (R2 config)
constexpr int NBLK      = SLICES * BPS;       // 1536 stage1 blocks
constexpr int V4_SLICE  = ELEMS / 4;          // 65536 float4 per slice
constexpr int V4_BLOCK  = V4_SLICE / BPS;     // 2048 float4 per block
constexpr int V4_THREAD = V4_BLOCK / TPB;     // 8 float4 per thread
constexpr int WS_FLOATS = 5 * NBLK;           // SoA partials: ws[comp][NBLK]

// MEASUREMENT ROUND 2: stage2 launched TWICE (idempotent — pure function of
// ws, rewrites identical out[0]). dur_us - 23.13 isolates the stage2 path.

// Five linear accumulators (targets are exactly {0,1}):
//   sp = Σ sigmoid(x)   pt = Σ sigmoid(x)·t   st = Σ t
//   sd = Σ (x−t)²       sdt = Σ (x−t)²·t
struct Acc { float sp, pt, st, sd, sdt; };

__device__ __forceinline__ void acc1(float x, float t, Acc& a) {
    float e  = __expf(-x);
    float p  = __builtin_amdgcn_rcpf(1.0f + e);  // sigmoid via v_rcp
    float d  = x - t;
    float d2 = d * d;
    a.sp += p;
    a.pt  = fmaf(p, t, a.pt);
    a.st += t;
    a.sd += d2;
    a.sdt = fmaf(d2, t, a.sdt);
}

__device__ __forceinline__ void waveReduce5(Acc& a) {
    #pragma unroll
    for (int off = 32; off > 0; off >>= 1) {
        a.sp  += __shfl_down(a.sp,  off, 64);
        a.pt  += __shfl_down(a.pt,  off, 64);
        a.st  += __shfl_down(a.st,  off, 64);
        a.sd  += __shfl_down(a.sd,  off, 64);
        a.sdt += __shfl_down(a.sdt, off, 64);
    }
}

// Stage 1: exactly R2's kernel.
__global__ __launch_bounds__(TPB) void stage1(const float4* __restrict__ lg,
                                              const float4* __restrict__ tg,
                                              float* __restrict__ ws) {
    const int blk  = blockIdx.x;
    const int tid  = (int)threadIdx.x;
    const int base = blk * V4_BLOCK + tid;
    Acc a{0.f, 0.f, 0.f, 0.f, 0.f};
    #pragma unroll
    for (int k = 0; k < V4_THREAD; ++k) {
        float4 x4 = lg[base + k * TPB];
        float4 t4 = tg[base + k * TPB];
        acc1(x4.x, t4.x, a); acc1(x4.y, t4.y, a);
        acc1(x4.z, t4.z, a); acc1(x4.w, t4.w, a);
    }
    waveReduce5(a);
    __shared__ float red[TPB / 64][5];
    const int wave = tid >> 6;
    if ((tid & 63) == 0) {
        red[wave][0] = a.sp; red[wave][1] = a.pt; red[wave][2] = a.st;
        red[wave][3] = a.sd; red[wave][4] = a.sdt;
    }
    __syncthreads();
    if (tid < 5) {
        float v = 0.f;
        #pragma unroll
        for (int w = 0; w < TPB / 64; ++w) v += red[w][tid];
        ws[tid * NBLK + blk] = v;
    }
}

// Stage 2: exactly R2's kernel.
__global__ __launch_bounds__(64) void stage2(const float* __restrict__ ws,
                                             float* __restrict__ out) {
    const int t = threadIdx.x;
    float dice = 0.f, mse = 0.f;
    if (t < SLICES) {
        float c[5];
        #pragma unroll
        for (int comp = 0; comp < 5; ++comp) {
            const float4* p = (const float4*)(ws + comp * NBLK + t * BPS);
            float4 s = {0.f, 0.f, 0.f, 0.f};
            #pragma unroll
            for (int k = 0; k < BPS / 4; ++k) {
                float4 v = p[k];
                s.x += v.x; s.y += v.y; s.z += v.z; s.w += v.w;
            }
            c[comp] = (s.x + s.y) + (s.z + s.w);
        }
        float sp = c[0], pt = c[1], st = c[2], sd = c[3], sdt = c[4];
        dice = (2.0f * pt + SMOOTHF) / (sp + st + SMOOTHF);
        float cp = st;
        float cn = (float)ELEMS - cp;
        float s1 = sdt, s0 = sd - sdt;
        float mp = (cp > 0.f) ? s1 / fmaxf(cp, 1.f) : 0.f;
        float mn = (cn > 0.f) ? s0 / fmaxf(cn, 1.f) : 0.f;
        mse = mp + mn;
    }
    #pragma unroll
    for (int off = 32; off > 0; off >>= 1) {
        dice += __shfl_down(dice, off, 64);
        mse  += __shfl_down(mse,  off, 64);
    }
    if (t == 0) {
        float dice_loss = 1.0f - dice / (float)SLICES;
        float mse_loss  = mse / (float)SLICES;
        out[0] = DICE_WF * dice_loss + (1.0f - DICE_WF) * mse_loss;
    }
}

extern "C" void kernel_launch(void* const* d_in, const int* in_sizes, int n_in,
                              void* d_out, int out_size, void* d_ws, size_t ws_size,
                              hipStream_t stream) {
    const float4* lg = (const float4*)d_in[0];
    const float4* tg = (const float4*)d_in[1];
    float* out = (float*)d_out;
    float* ws  = (float*)d_ws;
    stage1<<<NBLK, TPB, 0, stream>>>(lg, tg, ws);
    stage2<<<1, 64, 0, stream>>>(ws, out);     // measurement copy
    stage2<<<1, 64, 0, stream>>>(ws, out);     // idempotent rewrite
}